// Round 3
// baseline (3568.859 us; speedup 1.0000x reference)
//
#include <hip/hip_runtime.h>
#include <hip/hip_bf16.h>
#include <math.h>

#define Mq 50000
#define Hh 32
#define MHt 1600000
#define SLOPE 0.1f

#define GRID_K1 1024
#define GRID_SWEEP 2048

typedef __hip_bfloat16 bf16;

__device__ __forceinline__ float lrelu(float x) { return x >= 0.f ? x : SLOPE * x; }

// 64-wide dot: row is an LDS row (wave-uniform base -> broadcast reads), wc in VGPRs
__device__ __forceinline__ float dot64(const float* row, const float* wc, float acc) {
    #pragma unroll
    for (int k4 = 0; k4 < 16; ++k4) {
        float4 a4 = *reinterpret_cast<const float4*>(&row[k4*4]);
        acc = fmaf(a4.x, wc[4*k4+0], acc);
        acc = fmaf(a4.y, wc[4*k4+1], acc);
        acc = fmaf(a4.z, wc[4*k4+2], acc);
        acc = fmaf(a4.w, wc[4*k4+3], acc);
    }
    return acc;
}

// ---------------- K1: moments of nbrs (analytic bn1 stats) ----------------
__launch_bounds__(256)
__global__ void k1_moments(const float* __restrict__ q_pts, const float* __restrict__ s_pts,
                           const int* __restrict__ inds, float* __restrict__ part1) {
    float a0=0.f,a1=0.f,a2=0.f,q00=0.f,q01=0.f,q02=0.f,q11=0.f,q12=0.f,q22=0.f;
    int tid = blockIdx.x * 256 + threadIdx.x;
    for (int p = tid; p < MHt; p += GRID_K1 * 256) {
        int m = p >> 5;
        int idx = inds[p];
        float d0 = s_pts[idx*3+0] - q_pts[m*3+0];
        float d1 = s_pts[idx*3+1] - q_pts[m*3+1];
        float d2 = s_pts[idx*3+2] - q_pts[m*3+2];
        a0 += d0; a1 += d1; a2 += d2;
        q00 = fmaf(d0,d0,q00); q01 = fmaf(d0,d1,q01); q02 = fmaf(d0,d2,q02);
        q11 = fmaf(d1,d1,q11); q12 = fmaf(d1,d2,q12); q22 = fmaf(d2,d2,q22);
    }
    #pragma unroll
    for (int off = 32; off > 0; off >>= 1) {
        a0 += __shfl_down(a0,off); a1 += __shfl_down(a1,off); a2 += __shfl_down(a2,off);
        q00 += __shfl_down(q00,off); q01 += __shfl_down(q01,off); q02 += __shfl_down(q02,off);
        q11 += __shfl_down(q11,off); q12 += __shfl_down(q12,off); q22 += __shfl_down(q22,off);
    }
    __shared__ float sh[4][12];
    int lane = threadIdx.x & 63, wv = threadIdx.x >> 6;
    if (lane == 0) {
        float* r = sh[wv];
        r[0]=a0; r[1]=a1; r[2]=a2; r[3]=q00; r[4]=q01; r[5]=q02; r[6]=q11; r[7]=q12; r[8]=q22;
    }
    __syncthreads();
    if (threadIdx.x < 9) {
        float s = sh[0][threadIdx.x] + sh[1][threadIdx.x] + sh[2][threadIdx.x] + sh[3][threadIdx.x];
        part1[blockIdx.x * 16 + threadIdx.x] = s;   // stride 16 (padded)
    }
}

// ---------------- fin1: bn1 scale/shift from moments (1024 threads) ----------------
__global__ void kfin1(const float* __restrict__ part1, const float* __restrict__ W1,
                      const float* __restrict__ gam, const float* __restrict__ bet,
                      float* __restrict__ st) {
    __shared__ float shf[64][16];
    __shared__ double shd[9];
    int t = threadIdx.x;            // 1024 threads
    int col = t & 15, sl = t >> 4;  // 64 slices x 16 cols
    float acc = 0.f;
    for (int r = sl; r < GRID_K1; r += 64) acc += part1[r*16 + col];
    shf[sl][col] = acc;
    __syncthreads();
    if (t < 9) {
        double s = 0.0;
        for (int i = 0; i < 64; ++i) s += (double)shf[i][t];
        shd[t] = s;
    }
    __syncthreads();
    if (t < 64) {
        double S0=shd[0],S1=shd[1],S2=shd[2],P00=shd[3],P01=shd[4],P02=shd[5],P11=shd[6],P12=shd[7],P22=shd[8];
        double w0 = W1[t], w1 = W1[64+t], w2 = W1[128+t];
        double inv = 1.0 / (double)MHt;
        double mean = (S0*w0 + S1*w1 + S2*w2) * inv;
        double e2 = (P00*w0*w0 + P11*w1*w1 + P22*w2*w2 + 2.0*(P01*w0*w1 + P02*w0*w2 + P12*w1*w2)) * inv;
        double var = e2 - mean*mean;
        double scale = (double)gam[t] / sqrt(var + 1e-5);
        st[t] = (float)scale;
        st[64+t] = (float)((double)bet[t] - mean*scale);
    }
}

// ---------------- finS: bn scale/shift from sum/sumsq partials (1024 threads) ----------------
__global__ void kfinS(const float* __restrict__ partS, const float* __restrict__ gam,
                      const float* __restrict__ bet, float* __restrict__ st) {
    __shared__ float shf[8][128];
    __shared__ double shd[128];
    int t = threadIdx.x;             // 1024 threads
    int col = t & 127, sl = t >> 7;  // 8 slices x 128 cols
    float acc = 0.f;
    for (int r = sl; r < GRID_SWEEP; r += 8) acc += partS[r*128 + col];
    shf[sl][col] = acc;
    __syncthreads();
    if (t < 128) {
        double s = 0.0;
        #pragma unroll
        for (int i = 0; i < 8; ++i) s += (double)shf[i][t];
        shd[t] = s;
    }
    __syncthreads();
    if (t < 64) {
        double inv = 1.0 / (double)MHt;
        double mean = shd[t] * inv;
        double var = shd[64+t] * inv - mean*mean;
        double scale = (double)gam[t] / sqrt(var + 1e-5);
        st[t] = (float)scale;
        st[64+t] = (float)((double)bet[t] - mean*scale);
    }
}

// ---------------- K2 (both tiers): geom(bf16) = lrelu(bn1(nbrs@W1))@W2+b2 ; stats of v'=feats-geom ----------------
__launch_bounds__(256)
__global__ void k2_geom(const float* __restrict__ q_pts, const float* __restrict__ s_pts,
                        const float* __restrict__ s_feats, const int* __restrict__ inds,
                        const float* __restrict__ W1, const float* __restrict__ st1,
                        const float* __restrict__ W2, const float* __restrict__ b2,
                        bf16* __restrict__ geom, float* __restrict__ partS) {
    __shared__ float A1s[4][64];
    __shared__ float redS[256], redQ[256];
    const int tid = threadIdx.x, c = tid & 63, g = tid >> 6;
    float wcol[64];
    #pragma unroll
    for (int k = 0; k < 64; ++k) wcol[k] = W2[k*64 + c];
    const float w10 = W1[c], w11 = W1[64+c], w12 = W1[128+c];
    const float sc = st1[c], sf = st1[64+c], bias = b2[c];
    float accS = 0.f, accQ = 0.f;
    #pragma unroll 1
    for (int ch = blockIdx.x; ch < MHt/4; ch += GRID_SWEEP) {
        int p = ch*4 + g;
        int m = p >> 5;
        int idx = inds[p];
        float d0 = s_pts[idx*3+0] - q_pts[m*3+0];
        float d1 = s_pts[idx*3+1] - q_pts[m*3+1];
        float d2 = s_pts[idx*3+2] - q_pts[m*3+2];
        float x1 = d0*w10; x1 = fmaf(d1,w11,x1); x1 = fmaf(d2,w12,x1);
        A1s[g][c] = lrelu(fmaf(x1, sc, sf));
        __syncthreads();
        float gm = dot64(A1s[g], wcol, bias);
        bf16 gb_ = __float2bfloat16(gm);
        geom[(size_t)p*64 + c] = gb_;
        float gmr = __bfloat162float(gb_);           // stats on ROUNDED value (consistent w/ consumers)
        float vp = s_feats[idx*64 + c] - gmr;
        accS += vp; accQ = fmaf(vp, vp, accQ);
        __syncthreads();
    }
    redS[tid] = accS; redQ[tid] = accQ;
    __syncthreads();
    if (tid < 64) {
        partS[blockIdx.x*128 + tid]      = redS[tid]+redS[64+tid]+redS[128+tid]+redS[192+tid];
        partS[blockIdx.x*128 + 64 + tid] = redQ[tid]+redQ[64+tid]+redQ[128+tid]+redQ[192+tid];
    }
}

// =================== TIER C (ws >= 2 big buffers) ===================

__launch_bounds__(256)
__global__ void k3c(const float* __restrict__ s_feats, const int* __restrict__ inds,
                    const bf16* __restrict__ geom, const float* __restrict__ st2,
                    const float* __restrict__ W, const float* __restrict__ bW,
                    bf16* __restrict__ v2, float* __restrict__ partS) {
    __shared__ float Bs[4][64];
    __shared__ float v0s[64];
    __shared__ float redS[256], redQ[256];
    const int tid = threadIdx.x, c = tid & 63, g = tid >> 6;
    float wcol[64];
    #pragma unroll
    for (int k = 0; k < 64; ++k) wcol[k] = W[k*64 + c];
    const float sc = st2[c], sf = st2[64+c], bias = bW[c];
    float accS = 0.f, accQ = 0.f;
    #pragma unroll 1
    for (int m = blockIdx.x; m < Mq; m += GRID_SWEEP) {
        #pragma unroll 1
        for (int ci = 0; ci < 8; ++ci) {
            int p = m*32 + ci*4 + g;
            int idx = inds[p];
            float gmr = __bfloat162float(geom[(size_t)p*64 + c]);
            float vp = s_feats[idx*64 + c] - gmr;
            Bs[g][c] = lrelu(fmaf(vp, sc, sf));
            __syncthreads();
            float acc = dot64(Bs[g], wcol, bias);
            bf16 vb = __float2bfloat16(acc);
            v2[(size_t)p*64 + c] = vb;
            float vr = __bfloat162float(vb);
            if (ci == 0 && g == 0) v0s[c] = vr;       // rounded v2[m,0,c]
            __syncthreads();
            float qv = v0s[c] - gmr;
            accS += qv; accQ = fmaf(qv, qv, accQ);
        }
    }
    redS[tid] = accS; redQ[tid] = accQ;
    __syncthreads();
    if (tid < 64) {
        partS[blockIdx.x*128 + tid]      = redS[tid]+redS[64+tid]+redS[128+tid]+redS[192+tid];
        partS[blockIdx.x*128 + 64 + tid] = redQ[tid]+redQ[64+tid]+redQ[128+tid]+redQ[192+tid];
    }
}

// x2 aliases geom buffer (per-thread read-before-write; each (p,c) touched by exactly one thread)
__launch_bounds__(256)
__global__ void k4c(bf16* geomx, const bf16* __restrict__ v2,
                    const float* __restrict__ st3, const float* __restrict__ W,
                    float* __restrict__ partS) {
    __shared__ float As[4][64];
    __shared__ float v0s[64];
    __shared__ float redS[256], redQ[256];
    const int tid = threadIdx.x, c = tid & 63, g = tid >> 6;
    float wcol[64];
    #pragma unroll
    for (int k = 0; k < 64; ++k) wcol[k] = W[k*64 + c];
    const float sc = st3[c], sf = st3[64+c];
    float accS = 0.f, accQ = 0.f;
    #pragma unroll 1
    for (int m = blockIdx.x; m < Mq; m += GRID_SWEEP) {
        if (tid < 64) v0s[tid] = __bfloat162float(v2[(size_t)m*2048 + tid]);
        __syncthreads();
        #pragma unroll 1
        for (int ci = 0; ci < 8; ++ci) {
            int p = m*32 + ci*4 + g;
            float gmr = __bfloat162float(geomx[(size_t)p*64 + c]);
            float qv = v0s[c] - gmr;
            As[g][c] = lrelu(fmaf(qv, sc, sf));
            __syncthreads();
            float acc = dot64(As[g], wcol, 0.f);
            bf16 xb = __float2bfloat16(acc);
            geomx[(size_t)p*64 + c] = xb;             // x2 over geom
            float xr = __bfloat162float(xb);
            accS += xr; accQ = fmaf(xr, xr, accQ);
            __syncthreads();
        }
    }
    redS[tid] = accS; redQ[tid] = accQ;
    __syncthreads();
    if (tid < 64) {
        partS[blockIdx.x*128 + tid]      = redS[tid]+redS[64+tid]+redS[128+tid]+redS[192+tid];
        partS[blockIdx.x*128 + 64 + tid] = redQ[tid]+redQ[64+tid]+redQ[128+tid]+redQ[192+tid];
    }
}

__launch_bounds__(256)
__global__ void k5c(const bf16* __restrict__ x2, const bf16* __restrict__ v2,
                    const float* __restrict__ st4, const float* __restrict__ W2a,
                    const float* __restrict__ b2a, float* __restrict__ out) {
    __shared__ float A2s[32*68];
    __shared__ float Ws[512];
    __shared__ float a3s[32*8];
    __shared__ float wns[32*8];
    __shared__ float red[4][64];
    const int tid = threadIdx.x, c = tid & 63, g = tid >> 6;
    Ws[tid] = W2a[tid];
    Ws[256 + tid] = W2a[256 + tid];
    const float sc = st4[c], sf = st4[64+c];
    const int hj_h = tid >> 3, hj_j = tid & 7;
    #pragma unroll 1
    for (int m = blockIdx.x; m < Mq; m += GRID_SWEEP) {
        #pragma unroll
        for (int it = 0; it < 8; ++it) {
            int h = it*4 + g;
            float v = __bfloat162float(x2[((size_t)m*32 + h)*64 + c]);
            A2s[h*68 + c] = lrelu(fmaf(v, sc, sf));
        }
        __syncthreads();
        {
            float acc = b2a[hj_j];
            #pragma unroll
            for (int k4 = 0; k4 < 16; ++k4) {
                float4 a4 = *reinterpret_cast<const float4*>(&A2s[hj_h*68 + k4*4]);
                acc = fmaf(a4.x, Ws[(4*k4+0)*8 + hj_j], acc);
                acc = fmaf(a4.y, Ws[(4*k4+1)*8 + hj_j], acc);
                acc = fmaf(a4.z, Ws[(4*k4+2)*8 + hj_j], acc);
                acc = fmaf(a4.w, Ws[(4*k4+3)*8 + hj_j], acc);
            }
            a3s[hj_h*8 + hj_j] = acc;
        }
        __syncthreads();
        if (tid < 8) {
            int j = tid;
            float mx = -1e30f;
            for (int h = 0; h < 32; ++h) mx = fmaxf(mx, a3s[h*8 + j]);
            float sum = 0.f;
            for (int h = 0; h < 32; ++h) { float e = expf(a3s[h*8 + j] - mx); wns[h*8 + j] = e; sum += e; }
            float r = 1.f / sum;
            for (int h = 0; h < 32; ++h) wns[h*8 + j] *= r;
        }
        __syncthreads();
        {
            float acc = 0.f;
            int j = c >> 3;
            #pragma unroll
            for (int hh = 0; hh < 8; ++hh) {
                int h = g*8 + hh;
                acc = fmaf(__bfloat162float(v2[((size_t)m*32 + h)*64 + c]), wns[h*8 + j], acc);
            }
            red[g][c] = acc;
        }
        __syncthreads();
        if (tid < 64) out[(size_t)m*64 + tid] = red[0][tid] + red[1][tid] + red[2][tid] + red[3][tid];
        __syncthreads();
    }
}

// =================== TIER E (ws >= 1 big buffer): store geom bf16 + v2[:,0,:] fp32 ===================

// v20[m,c] = v2[m,0,c]; stats3 over q = v20 - geom (all h)
__launch_bounds__(256)
__global__ void k3e(const float* __restrict__ s_feats, const int* __restrict__ inds,
                    const bf16* __restrict__ geom, const float* __restrict__ st2,
                    const float* __restrict__ W, const float* __restrict__ bW,
                    float* __restrict__ v20, float* __restrict__ partS) {
    __shared__ float Bs[4][64];
    __shared__ float redS[256], redQ[256];
    const int tid = threadIdx.x, c = tid & 63, g = tid >> 6;
    float wcol[64];
    #pragma unroll
    for (int k = 0; k < 64; ++k) wcol[k] = W[k*64 + c];
    const float sc = st2[c], sf = st2[64+c], bias = bW[c];
    float accS = 0.f, accQ = 0.f;
    #pragma unroll 1
    for (int mb = blockIdx.x; mb < Mq/4; mb += GRID_SWEEP) {
        int m = mb*4 + g;
        size_t p0 = (size_t)m*32;
        int idx = inds[p0];
        float gm0 = __bfloat162float(geom[p0*64 + c]);
        float vp = s_feats[idx*64 + c] - gm0;
        Bs[g][c] = lrelu(fmaf(vp, sc, sf));
        __syncthreads();
        float v2v = dot64(Bs[g], wcol, bias);
        v20[(size_t)m*64 + c] = v2v;
        #pragma unroll 1
        for (int h = 0; h < 32; ++h) {
            float gm = __bfloat162float(geom[(p0 + h)*64 + c]);
            float qv = v2v - gm;
            accS += qv; accQ = fmaf(qv, qv, accQ);
        }
        __syncthreads();
    }
    redS[tid] = accS; redQ[tid] = accQ;
    __syncthreads();
    if (tid < 64) {
        partS[blockIdx.x*128 + tid]      = redS[tid]+redS[64+tid]+redS[128+tid]+redS[192+tid];
        partS[blockIdx.x*128 + 64 + tid] = redQ[tid]+redQ[64+tid]+redQ[128+tid]+redQ[192+tid];
    }
}

// stats4 over x2 = lrelu(bn3(v20-geom))@aW1 (recomputed, not stored)
__launch_bounds__(256)
__global__ void k4e(const bf16* __restrict__ geom, const float* __restrict__ v20,
                    const float* __restrict__ st3, const float* __restrict__ W,
                    float* __restrict__ partS) {
    __shared__ float As[4][64];
    __shared__ float v0s[64];
    __shared__ float redS[256], redQ[256];
    const int tid = threadIdx.x, c = tid & 63, g = tid >> 6;
    float wcol[64];
    #pragma unroll
    for (int k = 0; k < 64; ++k) wcol[k] = W[k*64 + c];
    const float sc = st3[c], sf = st3[64+c];
    float accS = 0.f, accQ = 0.f;
    #pragma unroll 1
    for (int m = blockIdx.x; m < Mq; m += GRID_SWEEP) {
        if (tid < 64) v0s[tid] = v20[(size_t)m*64 + tid];
        __syncthreads();
        #pragma unroll 1
        for (int ci = 0; ci < 8; ++ci) {
            int p = m*32 + ci*4 + g;
            float gmr = __bfloat162float(geom[(size_t)p*64 + c]);
            float qv = v0s[c] - gmr;
            As[g][c] = lrelu(fmaf(qv, sc, sf));
            __syncthreads();
            float x = dot64(As[g], wcol, 0.f);
            accS += x; accQ = fmaf(x, x, accQ);
            __syncthreads();
        }
    }
    redS[tid] = accS; redQ[tid] = accQ;
    __syncthreads();
    if (tid < 64) {
        partS[blockIdx.x*128 + tid]      = redS[tid]+redS[64+tid]+redS[128+tid]+redS[192+tid];
        partS[blockIdx.x*128 + 64 + tid] = redQ[tid]+redQ[64+tid]+redQ[128+tid]+redQ[192+tid];
    }
}

// final: recompute v2 (all h) and x2, then a3 -> softmax -> weighted sum
__launch_bounds__(256)
__global__ void k5e(const float* __restrict__ s_feats, const int* __restrict__ inds,
                    const bf16* __restrict__ geom, const float* __restrict__ v20,
                    const float* __restrict__ st2, const float* __restrict__ gW, const float* __restrict__ gb,
                    const float* __restrict__ st3, const float* __restrict__ aW1,
                    const float* __restrict__ st4, const float* __restrict__ W2a,
                    const float* __restrict__ b2a, float* __restrict__ out) {
    __shared__ float Vt[32][64];
    __shared__ float v0s[64];
    __shared__ float Bs[4][64];
    __shared__ float As[4][64];
    __shared__ float A2s[4][64];
    __shared__ float a3s[32*8];
    __shared__ float wns[32*8];
    __shared__ float Ws[512];
    __shared__ float red[4][64];
    const int tid = threadIdx.x, c = tid & 63, g = tid >> 6;
    float wG[64], wA[64];
    #pragma unroll
    for (int k = 0; k < 64; ++k) { wG[k] = gW[k*64 + c]; wA[k] = aW1[k*64 + c]; }
    Ws[tid] = W2a[tid];
    Ws[256 + tid] = W2a[256 + tid];
    const float sc2 = st2[c], sf2 = st2[64+c];
    const float sc3 = st3[c], sf3 = st3[64+c];
    const float sc4 = st4[c], sf4 = st4[64+c];
    const float gbias = gb[c];
    #pragma unroll 1
    for (int m = blockIdx.x; m < Mq; m += GRID_SWEEP) {
        if (tid < 64) v0s[tid] = v20[(size_t)m*64 + tid];
        __syncthreads();
        #pragma unroll 1
        for (int ci = 0; ci < 8; ++ci) {
            int h = ci*4 + g;
            int p = m*32 + h;
            int idx = inds[p];
            float gmr = __bfloat162float(geom[(size_t)p*64 + c]);
            float vp = s_feats[idx*64 + c] - gmr;
            Bs[g][c] = lrelu(fmaf(vp, sc2, sf2));
            float qv = v0s[c] - gmr;
            As[g][c] = lrelu(fmaf(qv, sc3, sf3));
            __syncthreads();
            Vt[h][c] = dot64(Bs[g], wG, gbias);
            float x2v = dot64(As[g], wA, 0.f);
            A2s[g][c] = lrelu(fmaf(x2v, sc4, sf4));
            __syncthreads();
            if (tid < 32) {
                int hh = tid >> 3, j = tid & 7;
                float acc = b2a[j];
                #pragma unroll
                for (int k = 0; k < 64; ++k) acc = fmaf(A2s[hh][k], Ws[k*8 + j], acc);
                a3s[(ci*4 + hh)*8 + j] = acc;
            }
            // next iteration's __syncthreads orders A2s reuse (a3 readers arrive before it)
        }
        __syncthreads();
        if (tid < 8) {
            int j = tid;
            float mx = -1e30f;
            for (int h = 0; h < 32; ++h) mx = fmaxf(mx, a3s[h*8 + j]);
            float sum = 0.f;
            for (int h = 0; h < 32; ++h) { float e = expf(a3s[h*8 + j] - mx); wns[h*8 + j] = e; sum += e; }
            float r = 1.f / sum;
            for (int h = 0; h < 32; ++h) wns[h*8 + j] *= r;
        }
        __syncthreads();
        {
            float acc = 0.f;
            int j = c >> 3;
            #pragma unroll
            for (int hh = 0; hh < 8; ++hh) {
                int h = g*8 + hh;
                acc = fmaf(Vt[h][c], wns[h*8 + j], acc);
            }
            red[g][c] = acc;
        }
        __syncthreads();
        if (tid < 64) out[(size_t)m*64 + tid] = red[0][tid] + red[1][tid] + red[2][tid] + red[3][tid];
        __syncthreads();
    }
}

extern "C" void kernel_launch(void* const* d_in, const int* in_sizes, int n_in,
                              void* d_out, int out_size, void* d_ws, size_t ws_size,
                              hipStream_t stream) {
    const float* q_pts   = (const float*)d_in[0];
    const float* s_pts   = (const float*)d_in[1];
    const float* s_feats = (const float*)d_in[2];
    const int*   inds    = (const int*)d_in[3];
    const float* dW1 = (const float*)d_in[4];
    const float* dbg = (const float*)d_in[5];
    const float* dbb = (const float*)d_in[6];
    const float* dW2 = (const float*)d_in[7];
    const float* db2 = (const float*)d_in[8];
    const float* gng = (const float*)d_in[9];
    const float* gnb = (const float*)d_in[10];
    const float* gW  = (const float*)d_in[11];
    const float* gb  = (const float*)d_in[12];
    const float* ang = (const float*)d_in[13];
    const float* anb = (const float*)d_in[14];
    const float* aW1 = (const float*)d_in[15];
    const float* abg = (const float*)d_in[16];
    const float* abb = (const float*)d_in[17];
    const float* aW2 = (const float*)d_in[18];
    const float* ab2 = (const float*)d_in[19];
    float* out = (float*)d_out;

    char* ws = (char*)d_ws;
    float* part1 = (float*)ws;                           // [0, 64KB)
    float* partS = (float*)(ws + (1<<20));               // [1MB, 2MB)
    float* st1   = (float*)(ws + (2<<20));               // 4 x 128 floats
    float* st2 = st1 + 128;
    float* st3 = st1 + 256;
    float* st4 = st1 + 384;
    float* v20  = (float*)(ws + (3<<20));                // 12.8 MB (tier E)
    const size_t offBig = (size_t)16 << 20;
    const size_t szG = (size_t)MHt * 64 * 2;             // 204.8 MB bf16
    bf16* geom = (bf16*)(ws + offBig);
    bf16* v2   = (bf16*)(ws + offBig + szG);
    const size_t needC = offBig + 2*szG;                 // ~426 MB
    const size_t needE = offBig + szG;                   // ~221 MB

    if (ws_size < needE) return;  // ws too small for any stored-geom path -> clean fail, informs next round

    k1_moments<<<GRID_K1, 256, 0, stream>>>(q_pts, s_pts, inds, part1);
    kfin1<<<1, 1024, 0, stream>>>(part1, dW1, dbg, dbb, st1);
    k2_geom<<<GRID_SWEEP, 256, 0, stream>>>(q_pts, s_pts, s_feats, inds, dW1, st1, dW2, db2, geom, partS);
    kfinS<<<1, 1024, 0, stream>>>(partS, gng, gnb, st2);

    if (ws_size >= needC) {
        k3c<<<GRID_SWEEP, 256, 0, stream>>>(s_feats, inds, geom, st2, gW, gb, v2, partS);
        kfinS<<<1, 1024, 0, stream>>>(partS, ang, anb, st3);
        k4c<<<GRID_SWEEP, 256, 0, stream>>>(geom, v2, st3, aW1, partS);   // x2 aliases geom
        kfinS<<<1, 1024, 0, stream>>>(partS, abg, abb, st4);
        k5c<<<GRID_SWEEP, 256, 0, stream>>>(geom /*=x2*/, v2, st4, aW2, ab2, out);
    } else {
        k3e<<<GRID_SWEEP, 256, 0, stream>>>(s_feats, inds, geom, st2, gW, gb, v20, partS);
        kfinS<<<1, 1024, 0, stream>>>(partS, ang, anb, st3);
        k4e<<<GRID_SWEEP, 256, 0, stream>>>(geom, v20, st3, aW1, partS);
        kfinS<<<1, 1024, 0, stream>>>(partS, abg, abb, st4);
        k5e<<<GRID_SWEEP, 256, 0, stream>>>(s_feats, inds, geom, v20, st2, gW, gb,
                                            st3, aW1, st4, aW2, ab2, out);
    }
}

// Round 5
// 2892.852 us; speedup vs baseline: 1.2337x; 1.2337x over previous
//
#include <hip/hip_runtime.h>
#include <hip/hip_bf16.h>
#include <hip/hip_fp16.h>
#include <math.h>

#define Mq 50000
#define Hh 32
#define MHt 1600000
#define SLOPE 0.1f

#define GRID_K1 1024
#define GRID_SWEEP 2048

typedef __hip_bfloat16 bf16;

__device__ __forceinline__ float lrelu(float x) { return x >= 0.f ? x : SLOPE * x; }

// 64-wide dot: row is an LDS row (wave-uniform base -> broadcast reads), wc in VGPRs
__device__ __forceinline__ float dot64(const float* row, const float* wc, float acc) {
    #pragma unroll
    for (int k4 = 0; k4 < 16; ++k4) {
        float4 a4 = *reinterpret_cast<const float4*>(&row[k4*4]);
        acc = fmaf(a4.x, wc[4*k4+0], acc);
        acc = fmaf(a4.y, wc[4*k4+1], acc);
        acc = fmaf(a4.z, wc[4*k4+2], acc);
        acc = fmaf(a4.w, wc[4*k4+3], acc);
    }
    return acc;
}

// ---------------- K1: moments of nbrs (analytic bn1 stats) ----------------
__launch_bounds__(256)
__global__ void k1_moments(const float* __restrict__ q_pts, const float* __restrict__ s_pts,
                           const int* __restrict__ inds, float* __restrict__ part1) {
    float a0=0.f,a1=0.f,a2=0.f,q00=0.f,q01=0.f,q02=0.f,q11=0.f,q12=0.f,q22=0.f;
    int tid = blockIdx.x * 256 + threadIdx.x;
    for (int p = tid; p < MHt; p += GRID_K1 * 256) {
        int m = p >> 5;
        int idx = inds[p];
        float d0 = s_pts[idx*3+0] - q_pts[m*3+0];
        float d1 = s_pts[idx*3+1] - q_pts[m*3+1];
        float d2 = s_pts[idx*3+2] - q_pts[m*3+2];
        a0 += d0; a1 += d1; a2 += d2;
        q00 = fmaf(d0,d0,q00); q01 = fmaf(d0,d1,q01); q02 = fmaf(d0,d2,q02);
        q11 = fmaf(d1,d1,q11); q12 = fmaf(d1,d2,q12); q22 = fmaf(d2,d2,q22);
    }
    #pragma unroll
    for (int off = 32; off > 0; off >>= 1) {
        a0 += __shfl_down(a0,off); a1 += __shfl_down(a1,off); a2 += __shfl_down(a2,off);
        q00 += __shfl_down(q00,off); q01 += __shfl_down(q01,off); q02 += __shfl_down(q02,off);
        q11 += __shfl_down(q11,off); q12 += __shfl_down(q12,off); q22 += __shfl_down(q22,off);
    }
    __shared__ float sh[4][12];
    int lane = threadIdx.x & 63, wv = threadIdx.x >> 6;
    if (lane == 0) {
        float* r = sh[wv];
        r[0]=a0; r[1]=a1; r[2]=a2; r[3]=q00; r[4]=q01; r[5]=q02; r[6]=q11; r[7]=q12; r[8]=q22;
    }
    __syncthreads();
    if (threadIdx.x < 9) {
        float s = sh[0][threadIdx.x] + sh[1][threadIdx.x] + sh[2][threadIdx.x] + sh[3][threadIdx.x];
        part1[blockIdx.x * 16 + threadIdx.x] = s;   // stride 16 (padded)
    }
}

// ---------------- fin1: bn1 scale/shift from moments (1024 threads) ----------------
__global__ void kfin1(const float* __restrict__ part1, const float* __restrict__ W1,
                      const float* __restrict__ gam, const float* __restrict__ bet,
                      float* __restrict__ st) {
    __shared__ float shf[64][16];
    __shared__ double shd[9];
    int t = threadIdx.x;            // 1024 threads
    int col = t & 15, sl = t >> 4;  // 64 slices x 16 cols
    float acc = 0.f;
    for (int r = sl; r < GRID_K1; r += 64) acc += part1[r*16 + col];
    shf[sl][col] = acc;
    __syncthreads();
    if (t < 9) {
        double s = 0.0;
        for (int i = 0; i < 64; ++i) s += (double)shf[i][t];
        shd[t] = s;
    }
    __syncthreads();
    if (t < 64) {
        double S0=shd[0],S1=shd[1],S2=shd[2],P00=shd[3],P01=shd[4],P02=shd[5],P11=shd[6],P12=shd[7],P22=shd[8];
        double w0 = W1[t], w1 = W1[64+t], w2 = W1[128+t];
        double inv = 1.0 / (double)MHt;
        double mean = (S0*w0 + S1*w1 + S2*w2) * inv;
        double e2 = (P00*w0*w0 + P11*w1*w1 + P22*w2*w2 + 2.0*(P01*w0*w1 + P02*w0*w2 + P12*w1*w2)) * inv;
        double var = e2 - mean*mean;
        double scale = (double)gam[t] / sqrt(var + 1e-5);
        st[t] = (float)scale;
        st[64+t] = (float)((double)bet[t] - mean*scale);
    }
}

// ---------------- finS: bn scale/shift from sum/sumsq partials (1024 threads) ----------------
__global__ void kfinS(const float* __restrict__ partS, const float* __restrict__ gam,
                      const float* __restrict__ bet, float* __restrict__ st) {
    __shared__ float shf[8][128];
    __shared__ double shd[128];
    int t = threadIdx.x;             // 1024 threads
    int col = t & 127, sl = t >> 7;  // 8 slices x 128 cols
    float acc = 0.f;
    for (int r = sl; r < GRID_SWEEP; r += 8) acc += partS[r*128 + col];
    shf[sl][col] = acc;
    __syncthreads();
    if (t < 128) {
        double s = 0.0;
        #pragma unroll
        for (int i = 0; i < 8; ++i) s += (double)shf[i][t];
        shd[t] = s;
    }
    __syncthreads();
    if (t < 64) {
        double inv = 1.0 / (double)MHt;
        double mean = shd[t] * inv;
        double var = shd[64+t] * inv - mean*mean;
        double scale = (double)gam[t] / sqrt(var + 1e-5);
        st[t] = (float)scale;
        st[64+t] = (float)((double)bet[t] - mean*scale);
    }
}

// ---------------- K2: geom(bf16) = lrelu(bn1(nbrs@W1))@W2+b2 ; stats of v'=feats-geom ----------------
__launch_bounds__(256)
__global__ void k2_geom(const float* __restrict__ q_pts, const float* __restrict__ s_pts,
                        const float* __restrict__ s_feats, const int* __restrict__ inds,
                        const float* __restrict__ W1, const float* __restrict__ st1,
                        const float* __restrict__ W2, const float* __restrict__ b2,
                        bf16* __restrict__ geom, float* __restrict__ partS) {
    __shared__ float A1s[4][64];
    __shared__ float redS[256], redQ[256];
    const int tid = threadIdx.x, c = tid & 63, g = tid >> 6;
    float wcol[64];
    #pragma unroll
    for (int k = 0; k < 64; ++k) wcol[k] = W2[k*64 + c];
    const float w10 = W1[c], w11 = W1[64+c], w12 = W1[128+c];
    const float sc = st1[c], sf = st1[64+c], bias = b2[c];
    float accS = 0.f, accQ = 0.f;
    #pragma unroll 1
    for (int ch = blockIdx.x; ch < MHt/4; ch += GRID_SWEEP) {
        int p = ch*4 + g;
        int m = p >> 5;
        int idx = inds[p];
        float d0 = s_pts[idx*3+0] - q_pts[m*3+0];
        float d1 = s_pts[idx*3+1] - q_pts[m*3+1];
        float d2 = s_pts[idx*3+2] - q_pts[m*3+2];
        float x1 = d0*w10; x1 = fmaf(d1,w11,x1); x1 = fmaf(d2,w12,x1);
        A1s[g][c] = lrelu(fmaf(x1, sc, sf));
        __syncthreads();
        float gm = dot64(A1s[g], wcol, bias);
        bf16 gb_ = __float2bfloat16(gm);
        geom[(size_t)p*64 + c] = gb_;
        float gmr = __bfloat162float(gb_);           // stats on ROUNDED value
        float vp = s_feats[idx*64 + c] - gmr;
        accS += vp; accQ = fmaf(vp, vp, accQ);
        __syncthreads();
    }
    redS[tid] = accS; redQ[tid] = accQ;
    __syncthreads();
    if (tid < 64) {
        partS[blockIdx.x*128 + tid]      = redS[tid]+redS[64+tid]+redS[128+tid]+redS[192+tid];
        partS[blockIdx.x*128 + 64 + tid] = redQ[tid]+redQ[64+tid]+redQ[128+tid]+redQ[192+tid];
    }
}

// =================== TIER C (ws >= ~412MB): store geom + v2, zero recompute ===================

__launch_bounds__(256)
__global__ void k3c(const float* __restrict__ s_feats, const int* __restrict__ inds,
                    const bf16* __restrict__ geom, const float* __restrict__ st2,
                    const float* __restrict__ W, const float* __restrict__ bW,
                    bf16* __restrict__ v2, float* __restrict__ partS) {
    __shared__ float Bs[4][64];
    __shared__ float v0s[64];
    __shared__ float redS[256], redQ[256];
    const int tid = threadIdx.x, c = tid & 63, g = tid >> 6;
    float wcol[64];
    #pragma unroll
    for (int k = 0; k < 64; ++k) wcol[k] = W[k*64 + c];
    const float sc = st2[c], sf = st2[64+c], bias = bW[c];
    float accS = 0.f, accQ = 0.f;
    #pragma unroll 1
    for (int m = blockIdx.x; m < Mq; m += GRID_SWEEP) {
        #pragma unroll 1
        for (int ci = 0; ci < 8; ++ci) {
            int p = m*32 + ci*4 + g;
            int idx = inds[p];
            float gmr = __bfloat162float(geom[(size_t)p*64 + c]);
            float vp = s_feats[idx*64 + c] - gmr;
            Bs[g][c] = lrelu(fmaf(vp, sc, sf));
            __syncthreads();
            float acc = dot64(Bs[g], wcol, bias);
            bf16 vb = __float2bfloat16(acc);
            v2[(size_t)p*64 + c] = vb;
            float vr = __bfloat162float(vb);
            if (ci == 0 && g == 0) v0s[c] = vr;
            __syncthreads();
            float qv = v0s[c] - gmr;
            accS += qv; accQ = fmaf(qv, qv, accQ);
        }
    }
    redS[tid] = accS; redQ[tid] = accQ;
    __syncthreads();
    if (tid < 64) {
        partS[blockIdx.x*128 + tid]      = redS[tid]+redS[64+tid]+redS[128+tid]+redS[192+tid];
        partS[blockIdx.x*128 + 64 + tid] = redQ[tid]+redQ[64+tid]+redQ[128+tid]+redQ[192+tid];
    }
}

__launch_bounds__(256)
__global__ void k4c(bf16* geomx, const bf16* __restrict__ v2,
                    const float* __restrict__ st3, const float* __restrict__ W,
                    float* __restrict__ partS) {
    __shared__ float As[4][64];
    __shared__ float v0s[64];
    __shared__ float redS[256], redQ[256];
    const int tid = threadIdx.x, c = tid & 63, g = tid >> 6;
    float wcol[64];
    #pragma unroll
    for (int k = 0; k < 64; ++k) wcol[k] = W[k*64 + c];
    const float sc = st3[c], sf = st3[64+c];
    float accS = 0.f, accQ = 0.f;
    #pragma unroll 1
    for (int m = blockIdx.x; m < Mq; m += GRID_SWEEP) {
        if (tid < 64) v0s[tid] = __bfloat162float(v2[(size_t)m*2048 + tid]);
        __syncthreads();
        #pragma unroll 1
        for (int ci = 0; ci < 8; ++ci) {
            int p = m*32 + ci*4 + g;
            float gmr = __bfloat162float(geomx[(size_t)p*64 + c]);
            float qv = v0s[c] - gmr;
            As[g][c] = lrelu(fmaf(qv, sc, sf));
            __syncthreads();
            float acc = dot64(As[g], wcol, 0.f);
            bf16 xb = __float2bfloat16(acc);
            geomx[(size_t)p*64 + c] = xb;             // x2 over geom (read-before-write, same thread)
            float xr = __bfloat162float(xb);
            accS += xr; accQ = fmaf(xr, xr, accQ);
            __syncthreads();
        }
    }
    redS[tid] = accS; redQ[tid] = accQ;
    __syncthreads();
    if (tid < 64) {
        partS[blockIdx.x*128 + tid]      = redS[tid]+redS[64+tid]+redS[128+tid]+redS[192+tid];
        partS[blockIdx.x*128 + 64 + tid] = redQ[tid]+redQ[64+tid]+redQ[128+tid]+redQ[192+tid];
    }
}

__launch_bounds__(256)
__global__ void k5c(const bf16* __restrict__ x2, const bf16* __restrict__ v2,
                    const float* __restrict__ st4, const float* __restrict__ W2a,
                    const float* __restrict__ b2a, float* __restrict__ out) {
    __shared__ float A2s[32*68];
    __shared__ float Ws[512];
    __shared__ float a3s[32*8];
    __shared__ float wns[32*8];
    __shared__ float red[4][64];
    const int tid = threadIdx.x, c = tid & 63, g = tid >> 6;
    Ws[tid] = W2a[tid];
    Ws[256 + tid] = W2a[256 + tid];
    const float sc = st4[c], sf = st4[64+c];
    const int hj_h = tid >> 3, hj_j = tid & 7;
    #pragma unroll 1
    for (int m = blockIdx.x; m < Mq; m += GRID_SWEEP) {
        #pragma unroll
        for (int it = 0; it < 8; ++it) {
            int h = it*4 + g;
            float v = __bfloat162float(x2[((size_t)m*32 + h)*64 + c]);
            A2s[h*68 + c] = lrelu(fmaf(v, sc, sf));
        }
        __syncthreads();
        {
            float acc = b2a[hj_j];
            #pragma unroll
            for (int k4 = 0; k4 < 16; ++k4) {
                float4 a4 = *reinterpret_cast<const float4*>(&A2s[hj_h*68 + k4*4]);
                acc = fmaf(a4.x, Ws[(4*k4+0)*8 + hj_j], acc);
                acc = fmaf(a4.y, Ws[(4*k4+1)*8 + hj_j], acc);
                acc = fmaf(a4.z, Ws[(4*k4+2)*8 + hj_j], acc);
                acc = fmaf(a4.w, Ws[(4*k4+3)*8 + hj_j], acc);
            }
            a3s[hj_h*8 + hj_j] = acc;
        }
        __syncthreads();
        if (tid < 8) {
            int j = tid;
            float mx = -1e30f;
            for (int h = 0; h < 32; ++h) mx = fmaxf(mx, a3s[h*8 + j]);
            float sum = 0.f;
            for (int h = 0; h < 32; ++h) { float e = expf(a3s[h*8 + j] - mx); wns[h*8 + j] = e; sum += e; }
            float r = 1.f / sum;
            for (int h = 0; h < 32; ++h) wns[h*8 + j] *= r;
        }
        __syncthreads();
        {
            float acc = 0.f;
            int j = c >> 3;
            #pragma unroll
            for (int hh = 0; hh < 8; ++hh) {
                int h = g*8 + hh;
                acc = fmaf(__bfloat162float(v2[((size_t)m*32 + h)*64 + c]), wns[h*8 + j], acc);
            }
            red[g][c] = acc;
        }
        __syncthreads();
        if (tid < 64) out[(size_t)m*64 + tid] = red[0][tid] + red[1][tid] + red[2][tid] + red[3][tid];
        __syncthreads();
    }
}

// =================== TIER E common: v20 + stats passes ===================

__launch_bounds__(256)
__global__ void k3e(const float* __restrict__ s_feats, const int* __restrict__ inds,
                    const bf16* __restrict__ geom, const float* __restrict__ st2,
                    const float* __restrict__ W, const float* __restrict__ bW,
                    float* __restrict__ v20, float* __restrict__ partS) {
    __shared__ float Bs[4][64];
    __shared__ float redS[256], redQ[256];
    const int tid = threadIdx.x, c = tid & 63, g = tid >> 6;
    float wcol[64];
    #pragma unroll
    for (int k = 0; k < 64; ++k) wcol[k] = W[k*64 + c];
    const float sc = st2[c], sf = st2[64+c], bias = bW[c];
    float accS = 0.f, accQ = 0.f;
    #pragma unroll 1
    for (int mb = blockIdx.x; mb < Mq/4; mb += GRID_SWEEP) {
        int m = mb*4 + g;
        size_t p0 = (size_t)m*32;
        int idx = inds[p0];
        float gm0 = __bfloat162float(geom[p0*64 + c]);
        float vp = s_feats[idx*64 + c] - gm0;
        Bs[g][c] = lrelu(fmaf(vp, sc, sf));
        __syncthreads();
        float v2v = dot64(Bs[g], wcol, bias);
        v20[(size_t)m*64 + c] = v2v;
        #pragma unroll 1
        for (int h = 0; h < 32; ++h) {
            float gm = __bfloat162float(geom[(p0 + h)*64 + c]);
            float qv = v2v - gm;
            accS += qv; accQ = fmaf(qv, qv, accQ);
        }
        __syncthreads();
    }
    redS[tid] = accS; redQ[tid] = accQ;
    __syncthreads();
    if (tid < 64) {
        partS[blockIdx.x*128 + tid]      = redS[tid]+redS[64+tid]+redS[128+tid]+redS[192+tid];
        partS[blockIdx.x*128 + 64 + tid] = redQ[tid]+redQ[64+tid]+redQ[128+tid]+redQ[192+tid];
    }
}

__launch_bounds__(256)
__global__ void k4e(const bf16* __restrict__ geom, const float* __restrict__ v20,
                    const float* __restrict__ st3, const float* __restrict__ W,
                    float* __restrict__ partS) {
    __shared__ float As[4][64];
    __shared__ float v0s[64];
    __shared__ float redS[256], redQ[256];
    const int tid = threadIdx.x, c = tid & 63, g = tid >> 6;
    float wcol[64];
    #pragma unroll
    for (int k = 0; k < 64; ++k) wcol[k] = W[k*64 + c];
    const float sc = st3[c], sf = st3[64+c];
    float accS = 0.f, accQ = 0.f;
    #pragma unroll 1
    for (int m = blockIdx.x; m < Mq; m += GRID_SWEEP) {
        if (tid < 64) v0s[tid] = v20[(size_t)m*64 + tid];
        __syncthreads();
        #pragma unroll 1
        for (int ci = 0; ci < 8; ++ci) {
            int p = m*32 + ci*4 + g;
            float gmr = __bfloat162float(geom[(size_t)p*64 + c]);
            float qv = v0s[c] - gmr;
            As[g][c] = lrelu(fmaf(qv, sc, sf));
            __syncthreads();
            float x = dot64(As[g], wcol, 0.f);
            accS += x; accQ = fmaf(x, x, accQ);
            __syncthreads();
        }
    }
    redS[tid] = accS; redQ[tid] = accQ;
    __syncthreads();
    if (tid < 64) {
        partS[blockIdx.x*128 + tid]      = redS[tid]+redS[64+tid]+redS[128+tid]+redS[192+tid];
        partS[blockIdx.x*128 + 64 + tid] = redQ[tid]+redQ[64+tid]+redQ[128+tid]+redQ[192+tid];
    }
}

// =================== TIER E2 (ws >= ~247MB): split weights/output kernels, NO spill ===================

// k5w: x2 = lrelu(bn3(v20-geom))@aW1 ; a2=lrelu(bn4(x2)) ; a3=a2@aW2+b ; softmax -> wnsG (fp16)
__launch_bounds__(256)
__global__ void k5w(const bf16* __restrict__ geom, const float* __restrict__ v20,
                    const float* __restrict__ st3, const float* __restrict__ aW1,
                    const float* __restrict__ st4, const float* __restrict__ W2a,
                    const float* __restrict__ b2a, __half* __restrict__ wnsG) {
    __shared__ float As[4][64];
    __shared__ float A2s[4][64];
    __shared__ float a3s[32*8];
    __shared__ float wns_s[32*8];
    __shared__ float Ws[512];
    __shared__ float v0s[64];
    const int tid = threadIdx.x, c = tid & 63, g = tid >> 6;
    float wA[64];
    #pragma unroll
    for (int k = 0; k < 64; ++k) wA[k] = aW1[k*64 + c];
    Ws[tid] = W2a[tid];
    Ws[256 + tid] = W2a[256 + tid];
    const float sc3 = st3[c], sf3 = st3[64+c];
    const float sc4 = st4[c], sf4 = st4[64+c];
    #pragma unroll 1
    for (int m = blockIdx.x; m < Mq; m += GRID_SWEEP) {
        if (tid < 64) v0s[tid] = v20[(size_t)m*64 + tid];
        __syncthreads();
        #pragma unroll 1
        for (int ci = 0; ci < 8; ++ci) {
            int p = m*32 + ci*4 + g;
            float gmr = __bfloat162float(geom[(size_t)p*64 + c]);
            float qv = v0s[c] - gmr;
            As[g][c] = lrelu(fmaf(qv, sc3, sf3));
            __syncthreads();
            float x2v = dot64(As[g], wA, 0.f);
            A2s[g][c] = lrelu(fmaf(x2v, sc4, sf4));
            __syncthreads();
            if (tid < 32) {
                int hh = tid >> 3, j = tid & 7;
                float acc = b2a[j];
                #pragma unroll
                for (int k = 0; k < 64; ++k) acc = fmaf(A2s[hh][k], Ws[k*8 + j], acc);
                a3s[(ci*4 + hh)*8 + j] = acc;
            }
            // A2s rewrite happens after next iteration's first sync -> a3 reads are safe
        }
        __syncthreads();
        if (tid < 8) {
            int j = tid;
            float mx = -1e30f;
            for (int h = 0; h < 32; ++h) mx = fmaxf(mx, a3s[h*8 + j]);
            float sum = 0.f;
            for (int h = 0; h < 32; ++h) { float e = expf(a3s[h*8 + j] - mx); wns_s[h*8 + j] = e; sum += e; }
            float r = 1.f / sum;
            for (int h = 0; h < 32; ++h) wns_s[h*8 + j] *= r;
        }
        __syncthreads();
        wnsG[(size_t)m*256 + tid] = __float2half(wns_s[tid]);   // layout h*8+j
        __syncthreads();
    }
}

// k6w: recompute v2 = lrelu(bn2(feats-geom))@gW+gb ; out = sum_h v2 * wns
__launch_bounds__(256)
__global__ void k6w(const float* __restrict__ s_feats, const int* __restrict__ inds,
                    const bf16* __restrict__ geom, const float* __restrict__ st2,
                    const float* __restrict__ gW, const float* __restrict__ gb,
                    const __half* __restrict__ wnsG, float* __restrict__ out) {
    __shared__ float Bs[4][64];
    __shared__ float wns_s[256];
    __shared__ float red[4][64];
    const int tid = threadIdx.x, c = tid & 63, g = tid >> 6;
    float wG[64];
    #pragma unroll
    for (int k = 0; k < 64; ++k) wG[k] = gW[k*64 + c];
    const float sc2 = st2[c], sf2 = st2[64+c];
    const float gbias = gb[c];
    const int j = c >> 3;
    #pragma unroll 1
    for (int m = blockIdx.x; m < Mq; m += GRID_SWEEP) {
        wns_s[tid] = __half2float(wnsG[(size_t)m*256 + tid]);
        __syncthreads();
        float accO = 0.f;
        #pragma unroll 1
        for (int ci = 0; ci < 8; ++ci) {
            int h = ci*4 + g;
            int p = m*32 + h;
            int idx = inds[p];
            float gmr = __bfloat162float(geom[(size_t)p*64 + c]);
            float vp = s_feats[idx*64 + c] - gmr;
            Bs[g][c] = lrelu(fmaf(vp, sc2, sf2));
            __syncthreads();
            float v2v = dot64(Bs[g], wG, gbias);
            accO = fmaf(v2v, wns_s[h*8 + j], accO);
            __syncthreads();
        }
        red[g][c] = accO;
        __syncthreads();
        if (tid < 64) out[(size_t)m*64 + tid] = red[0][tid] + red[1][tid] + red[2][tid] + red[3][tid];
        __syncthreads();
    }
}

// =================== TIER E fallback (round-3 k5e, known-working) ===================
__launch_bounds__(256)
__global__ void k5e(const float* __restrict__ s_feats, const int* __restrict__ inds,
                    const bf16* __restrict__ geom, const float* __restrict__ v20,
                    const float* __restrict__ st2, const float* __restrict__ gW, const float* __restrict__ gb,
                    const float* __restrict__ st3, const float* __restrict__ aW1,
                    const float* __restrict__ st4, const float* __restrict__ W2a,
                    const float* __restrict__ b2a, float* __restrict__ out) {
    __shared__ float Vt[32][64];
    __shared__ float v0s[64];
    __shared__ float Bs[4][64];
    __shared__ float As[4][64];
    __shared__ float A2s[4][64];
    __shared__ float a3s[32*8];
    __shared__ float wns[32*8];
    __shared__ float Ws[512];
    __shared__ float red[4][64];
    const int tid = threadIdx.x, c = tid & 63, g = tid >> 6;
    float wG[64], wA[64];
    #pragma unroll
    for (int k = 0; k < 64; ++k) { wG[k] = gW[k*64 + c]; wA[k] = aW1[k*64 + c]; }
    Ws[tid] = W2a[tid];
    Ws[256 + tid] = W2a[256 + tid];
    const float sc2 = st2[c], sf2 = st2[64+c];
    const float sc3 = st3[c], sf3 = st3[64+c];
    const float sc4 = st4[c], sf4 = st4[64+c];
    const float gbias = gb[c];
    #pragma unroll 1
    for (int m = blockIdx.x; m < Mq; m += GRID_SWEEP) {
        if (tid < 64) v0s[tid] = v20[(size_t)m*64 + tid];
        __syncthreads();
        #pragma unroll 1
        for (int ci = 0; ci < 8; ++ci) {
            int h = ci*4 + g;
            int p = m*32 + h;
            int idx = inds[p];
            float gmr = __bfloat162float(geom[(size_t)p*64 + c]);
            float vp = s_feats[idx*64 + c] - gmr;
            Bs[g][c] = lrelu(fmaf(vp, sc2, sf2));
            float qv = v0s[c] - gmr;
            As[g][c] = lrelu(fmaf(qv, sc3, sf3));
            __syncthreads();
            Vt[h][c] = dot64(Bs[g], wG, gbias);
            float x2v = dot64(As[g], wA, 0.f);
            A2s[g][c] = lrelu(fmaf(x2v, sc4, sf4));
            __syncthreads();
            if (tid < 32) {
                int hh = tid >> 3, j = tid & 7;
                float acc = b2a[j];
                #pragma unroll
                for (int k = 0; k < 64; ++k) acc = fmaf(A2s[hh][k], Ws[k*8 + j], acc);
                a3s[(ci*4 + hh)*8 + j] = acc;
            }
        }
        __syncthreads();
        if (tid < 8) {
            int j = tid;
            float mx = -1e30f;
            for (int h = 0; h < 32; ++h) mx = fmaxf(mx, a3s[h*8 + j]);
            float sum = 0.f;
            for (int h = 0; h < 32; ++h) { float e = expf(a3s[h*8 + j] - mx); wns[h*8 + j] = e; sum += e; }
            float r = 1.f / sum;
            for (int h = 0; h < 32; ++h) wns[h*8 + j] *= r;
        }
        __syncthreads();
        {
            float acc = 0.f;
            int j = c >> 3;
            #pragma unroll
            for (int hh = 0; hh < 8; ++hh) {
                int h = g*8 + hh;
                acc = fmaf(Vt[h][c], wns[h*8 + j], acc);
            }
            red[g][c] = acc;
        }
        __syncthreads();
        if (tid < 64) out[(size_t)m*64 + tid] = red[0][tid] + red[1][tid] + red[2][tid] + red[3][tid];
        __syncthreads();
    }
}

extern "C" void kernel_launch(void* const* d_in, const int* in_sizes, int n_in,
                              void* d_out, int out_size, void* d_ws, size_t ws_size,
                              hipStream_t stream) {
    const float* q_pts   = (const float*)d_in[0];
    const float* s_pts   = (const float*)d_in[1];
    const float* s_feats = (const float*)d_in[2];
    const int*   inds    = (const int*)d_in[3];
    const float* dW1 = (const float*)d_in[4];
    const float* dbg = (const float*)d_in[5];
    const float* dbb = (const float*)d_in[6];
    const float* dW2 = (const float*)d_in[7];
    const float* db2 = (const float*)d_in[8];
    const float* gng = (const float*)d_in[9];
    const float* gnb = (const float*)d_in[10];
    const float* gW  = (const float*)d_in[11];
    const float* gb  = (const float*)d_in[12];
    const float* ang = (const float*)d_in[13];
    const float* anb = (const float*)d_in[14];
    const float* aW1 = (const float*)d_in[15];
    const float* abg = (const float*)d_in[16];
    const float* abb = (const float*)d_in[17];
    const float* aW2 = (const float*)d_in[18];
    const float* ab2 = (const float*)d_in[19];
    float* out = (float*)d_out;

    char* ws = (char*)d_ws;
    float* part1 = (float*)ws;                           // 64KB
    float* partS = (float*)(ws + (1<<20));               // 1MB
    float* st1   = (float*)(ws + (2<<20));
    float* st2 = st1 + 128;
    float* st3 = st1 + 256;
    float* st4 = st1 + 384;
    float* v20  = (float*)(ws + (3<<20));                // 12.8MB (tier E)
    const size_t szG = (size_t)MHt * 64 * 2;             // 204.8MB bf16

    // Tier C layout: geomC @2MB, v2C right after (v20 unused)
    bf16* geomC = (bf16*)(ws + (2<<20) + 4096);
    bf16* v2C   = geomC + (size_t)MHt * 64;
    const size_t needC = (2<<20) + 4096 + 2*szG;         // ~411.6MB

    // Tier E layout: geom @16MB, wns (fp16) after
    bf16*  geom = (bf16*)(ws + ((size_t)16<<20));
    __half* wnsG = (__half*)(ws + ((size_t)16<<20) + szG);
    const size_t needE2 = ((size_t)16<<20) + szG + (size_t)Mq*256*2;  // ~246.4MB
    const size_t needE  = ((size_t)16<<20) + szG;                     // ~220.8MB

    if (ws_size < needE) return;

    k1_moments<<<GRID_K1, 256, 0, stream>>>(q_pts, s_pts, inds, part1);
    kfin1<<<1, 1024, 0, stream>>>(part1, dW1, dbg, dbb, st1);

    if (ws_size >= needC) {
        k2_geom<<<GRID_SWEEP, 256, 0, stream>>>(q_pts, s_pts, s_feats, inds, dW1, st1, dW2, db2, geomC, partS);
        kfinS<<<1, 1024, 0, stream>>>(partS, gng, gnb, st2);
        k3c<<<GRID_SWEEP, 256, 0, stream>>>(s_feats, inds, geomC, st2, gW, gb, v2C, partS);
        kfinS<<<1, 1024, 0, stream>>>(partS, ang, anb, st3);
        k4c<<<GRID_SWEEP, 256, 0, stream>>>(geomC, v2C, st3, aW1, partS);   // x2 aliases geomC
        kfinS<<<1, 1024, 0, stream>>>(partS, abg, abb, st4);
        k5c<<<GRID_SWEEP, 256, 0, stream>>>(geomC /*=x2*/, v2C, st4, aW2, ab2, out);
    } else {
        k2_geom<<<GRID_SWEEP, 256, 0, stream>>>(q_pts, s_pts, s_feats, inds, dW1, st1, dW2, db2, geom, partS);
        kfinS<<<1, 1024, 0, stream>>>(partS, gng, gnb, st2);
        k3e<<<GRID_SWEEP, 256, 0, stream>>>(s_feats, inds, geom, st2, gW, gb, v20, partS);
        kfinS<<<1, 1024, 0, stream>>>(partS, ang, anb, st3);
        k4e<<<GRID_SWEEP, 256, 0, stream>>>(geom, v20, st3, aW1, partS);
        kfinS<<<1, 1024, 0, stream>>>(partS, abg, abb, st4);
        if (ws_size >= needE2) {
            k5w<<<GRID_SWEEP, 256, 0, stream>>>(geom, v20, st3, aW1, st4, aW2, ab2, wnsG);
            k6w<<<GRID_SWEEP, 256, 0, stream>>>(s_feats, inds, geom, st2, gW, gb, wnsG, out);
        } else {
            k5e<<<GRID_SWEEP, 256, 0, stream>>>(s_feats, inds, geom, v20, st2, gW, gb,
                                                st3, aW1, st4, aW2, ab2, out);
        }
    }
}